// Round 10
// baseline (256.119 us; speedup 1.0000x reference)
//
#include <hip/hip_runtime.h>

typedef __attribute__((ext_vector_type(8))) short short8;
typedef __attribute__((ext_vector_type(4))) float f32x4;
typedef __attribute__((ext_vector_type(16))) float f32x16;
typedef __attribute__((ext_vector_type(2))) unsigned int u32x2;
typedef __attribute__((ext_vector_type(4))) unsigned int u32x4;
typedef unsigned short u16;
typedef unsigned int u32;

#define MFMA16(a, b, c) __builtin_amdgcn_mfma_f32_16x16x32_bf16((a), (b), (c), 0, 0, 0)
#define MFMA32(a, b, c) __builtin_amdgcn_mfma_f32_32x32x16_bf16((a), (b), (c), 0, 0, 0)

#define BATCH 8
#define NTOK 4096
#define CDIM 256
#define CQK 32
#define LOG2E 1.4426950408889634f

__device__ __forceinline__ u16 f2bf(float f) {
  u32 u = __float_as_uint(f);
  return (u16)((u + 0x7FFFu + ((u >> 16) & 1u)) >> 16);
}
// pack two f32 -> two bf16 (round-half-up) in one u32: bf(a) | bf(b)<<16
__device__ __forceinline__ u32 pack2(float a, float b) {
  const u32 ua = __float_as_uint(a) + 0x8000u;
  const u32 ub = __float_as_uint(b) + 0x8000u;
#if __has_builtin(__builtin_amdgcn_perm)
  return __builtin_amdgcn_perm(ub, ua, 0x07060302u);  // {ua.b2,ua.b3,ub.b2,ub.b3}
#else
  return (ua >> 16) | (ub & 0xFFFF0000u);
#endif
}
__device__ __forceinline__ float fexp2(float x) {
#if __has_builtin(__builtin_amdgcn_exp2f)
  return __builtin_amdgcn_exp2f(x);
#else
  return exp2f(x);
#endif
}

// ---------------------------------------------------------------------------
// Kernel 0: weights -> MFMA B-fragment order + f32 bias.
// ---------------------------------------------------------------------------
__global__ void k_prep(const float* __restrict__ Wq, const float* __restrict__ bq,
                       const float* __restrict__ Wk, const float* __restrict__ bk,
                       const float* __restrict__ Wv, const float* __restrict__ bv,
                       u16* __restrict__ wtf, float* __restrict__ bias) {
  const int f = blockIdx.x;        // 0..159 = ct*8+ks
  const int L = threadIdx.x;       // 0..63
  const int ct = f >> 3, ks = f & 7;
  const int o = ct * 16 + (L & 15);
  const int ch = ks * 32 + (L >> 4) * 8;
  short8 v8;
#pragma unroll
  for (int jj = 0; jj < 8; jj++) {
    const int c = ch + jj;
    float v;
    if (o < 32)       v = Wq[c * CQK + o];
    else if (o < 64)  v = Wk[c * CQK + (o - 32)];
    else              v = Wv[c * CDIM + (o - 64)];
    v8[jj] = (short)f2bf(v);
  }
  *(short8*)(wtf + (size_t)f * 512 + L * 8) = v8;
  if (f == 0) {
    for (int i = L; i < 320; i += 64) {
      if (i < 32)      bias[i] = bq[i];
      else if (i < 64) bias[i] = bk[i - 32];
      else             bias[i] = bv[i - 64];
    }
  }
}

// ---------------------------------------------------------------------------
// Kernel 1: fused cvt+proj. K outputs pre-scaled by log2(e) (exp2 trick).
// q_ws/k_ws row-major [row][32]. V is emitted as ready MFMA32 B-fragments
// with the in-register-P j-permutation baked in:
//   frag(b, t=64-token tile, cg=64-ch group, fid=(jt<<2)|(kh<<1)|ct2):
//   lane l, elem jj holds V[t*64 + 32*jt + 16*kh + 4*(l>>5) + (jj&3)+8*(jj>>2)]
//                          [cg*64 + ct2*32 + (l&31)]
// so k_attn's PV consumes V global->reg with zero LDS staging and the A/B
// k-orders agree by construction (j(k) = (k&3)+8*((k>>2)&1)+4*(k>>3)).
// ---------------------------------------------------------------------------
__global__ __launch_bounds__(256, 2) void k_proj(
    const float* __restrict__ x, const u16* __restrict__ wtf,
    const float* __restrict__ bias,
    u16* __restrict__ q_ws, u16* __restrict__ k_ws, u16* __restrict__ vt_ws) {
  __shared__ u16 x_lds[64 * 264];
  __shared__ u16 vt_t[64 * 76];   // straight [c][n], pad 76 (2-way banks)
  const int m0 = blockIdx.x * 64;
  const int tid = threadIdx.x;
  const int w = tid >> 6, L = tid & 63;
  const int lr = L & 15, q4 = L >> 4;

  // ks=0 weight prefetch (independent of LDS) — flies across the x staging.
  short8 wfA[5], wfB[5];
#pragma unroll
  for (int j = 0; j < 5; j++)
    wfA[j] = *(const short8*)(wtf + ((size_t)((j * 4 + w) * 8 + 0)) * 512 + L * 8);

  // stage + convert x tile via perm-packs
#pragma unroll
  for (int ii = 0; ii < 8; ii++) {
    const int e = (tid + 256 * ii) * 8;
    const int row = e >> 8, col = e & 255;
    const float* src = x + (size_t)(m0 + row) * CDIM + col;
    f32x4 a = *(const f32x4*)src;
    f32x4 b4 = *(const f32x4*)(src + 4);
    u32x4 pk;
    pk[0] = pack2(a[0], a[1]);
    pk[1] = pack2(a[2], a[3]);
    pk[2] = pack2(b4[0], b4[1]);
    pk[3] = pack2(b4[2], b4[3]);
    *(u32x4*)&x_lds[row * 264 + col] = pk;
  }
  __syncthreads();

  f32x4 acc[4][5];
#pragma unroll
  for (int rg = 0; rg < 4; rg++)
#pragma unroll
    for (int j = 0; j < 5; j++) acc[rg][j] = (f32x4){0.f, 0.f, 0.f, 0.f};

#pragma unroll
  for (int ks = 0; ks < 8; ks++) {
    // prefetch next ks-slice into the other buffer (no barriers in this loop)
    if (ks < 7) {
#pragma unroll
      for (int j = 0; j < 5; j++) {
        short8 v = *(const short8*)(wtf +
            ((size_t)((j * 4 + w) * 8 + ks + 1)) * 512 + L * 8);
        if (ks & 1) wfA[j] = v; else wfB[j] = v;
      }
    }
#pragma unroll
    for (int rg = 0; rg < 4; rg++) {
      short8 a = *(const short8*)&x_lds[(rg * 16 + lr) * 264 + ks * 32 + q4 * 8];
#pragma unroll
      for (int j = 0; j < 5; j++)
        acc[rg][j] = MFMA16(a, (ks & 1) ? wfB[j] : wfA[j], acc[rg][j]);
    }
  }

  // q/k epilogue (j=0 -> ct = w; k scaled by log2e). Branch is wave-uniform.
  {
    const float bb = bias[w * 16 + lr];
#pragma unroll
    for (int rg = 0; rg < 4; rg++)
#pragma unroll
      for (int r = 0; r < 4; r++) {
        const int row = m0 + rg * 16 + q4 * 4 + r;
        float v = acc[rg][0][r] + bb;
        if (w < 2) q_ws[(size_t)row * CQK + w * 16 + lr] = f2bf(v);
        else       k_ws[(size_t)row * CQK + (w - 2) * 16 + lr] = f2bf(v * LOG2E);
      }
  }
  // v epilogue: straight transpose via LDS, then B-frag-linear store with
  // the PV j-permutation baked into the gather.
  const int b = m0 >> 12, nt = (m0 & 4095) >> 6;
  const int c_l = w * 16 + lr;
#pragma unroll
  for (int cg = 0; cg < 4; cg++) {
    __syncthreads();
    const int j = cg + 1;
    const float bb = bias[(4 + cg * 4 + w) * 16 + lr];
#pragma unroll
    for (int rg = 0; rg < 4; rg++) {
      u32x2 pk;
      pk[0] = pack2(acc[rg][j][0] + bb, acc[rg][j][1] + bb);
      pk[1] = pack2(acc[rg][j][2] + bb, acc[rg][j][3] + bb);
      *(u32x2*)&vt_t[c_l * 76 + rg * 16 + q4 * 4] = pk;   // straight n
    }
    __syncthreads();
    // fid is wave-uniform per store; lane gathers its 8 permuted tokens.
#pragma unroll
    for (int i = 0; i < 2; i++) {
      const int gch = tid + 256 * i;
      const int fid = gch >> 6;           // (jt<<2)|(kh<<1)|ct2
      const int lane = gch & 63;
      const int jt = fid >> 2, kh = (fid >> 1) & 1, ct2 = fid & 1;
      const int cc = ct2 * 32 + (lane & 31);
      const int n0 = jt * 32 + kh * 16 + (lane >> 5) * 4;
      u32x2 va = *(const u32x2*)&vt_t[cc * 76 + n0];       // tokens n0..n0+3
      u32x2 vb2 = *(const u32x2*)&vt_t[cc * 76 + n0 + 8];  // tokens n0+8..+11
      u32x4 vv = {va[0], va[1], vb2[0], vb2[1]};
      *(short8*)(vt_ws +
          ((((size_t)(b * 64 + nt) * 4 + cg) * 8 + fid) * 512) + lane * 8) =
          __builtin_bit_cast(short8, vv);
    }
  }
}

// ---------------------------------------------------------------------------
// Kernel 2: flash attention, in-register P, J-SPLIT for TLP: block = (b, 32
// i-rows), grid 1024 (4 blocks/CU); wave w: ch-half = w&1, j-half = w>>1.
// Work per (i,j,ch-half) chip-wide identical to r9 (duplication stays 2x);
// wave count doubles 2048->4096 -> 16 waves/CU (r9 was grid-limited at 8,
// latency-bound with 31% MfmaUtil and nothing saturated). Hot loop has no
// barriers; waves fully independent. Live V-frags halved 16->8 (reloads
// interleaved mid-EPPV right after each frag's last MFMA: ~300cyc to next
// use covers L2) to fit 4 waves/SIMD register budget. End: O/rowsum partial
// merge across j-half wave pairs via padded LDS (one barrier, once).
// ---------------------------------------------------------------------------
__global__ __launch_bounds__(256, 4) void k_attn(
    const float* __restrict__ x, const u16* __restrict__ q_ws,
    const u16* __restrict__ k_ws, const u16* __restrict__ vt_ws,
    const float* __restrict__ gamma, float* __restrict__ out) {
  __shared__ float obuf[2][64][65];     // j-half O partials (stride-65: no conflicts)
  __shared__ float rbuf[2][32];         // j-half rowsum partials
  __shared__ float lp2[2][32];          // 1/rowsum redistribution

  const int bid = blockIdx.x;
  const int b = bid & 7;                // same-b blocks land on one XCD
  const int i0 = (bid >> 3) * 32;       // 32-i window per block
  const int tid = threadIdx.x;
  const int w = tid >> 6, L = tid & 63;
  const int L31 = L & 31, Lhi = L >> 5;
  const int chh = w & 1;                // 128-ch half
  const int jsel = w >> 1;              // j-half: t in [jsel*32, jsel*32+32)
  const int t0 = jsel * 32;

  // K^T B-frags (persistent): lane holds K[i0+L31][Lhi*8 ..+8 (+16)]
  const u16* kb = k_ws + ((size_t)(b * NTOK + i0 + L31)) * CQK + Lhi * 8;
  const short8 kf0 = *(const short8*)(kb);
  const short8 kf1 = *(const short8*)(kb + 16);
  // Q A-frags: lane holds Q[j0+L31][Lhi*8 ..+8 (+16)]
  const u16* qb = q_ws + ((size_t)(b * NTOK) + L31) * CQK + Lhi * 8;
  // V frag base for this wave's 128-ch half (cg = chh*2 + cb2):
  //   + t*16384 + cb2*4096 + fid*512, fid = (jt<<2)|(kh<<1)|ct2
  const u16* vb = vt_ws + ((size_t)b << 20) + (size_t)(chh * 2) * 4096 +
                  (size_t)L * 8;

  f32x16 z16;
#pragma unroll
  for (int e = 0; e < 16; e++) z16[e] = 0.f;
  f32x16 o00 = z16, o01 = z16, o10 = z16, o11 = z16;  // [cb2][ct2]
  float ls = 0.f;

  // prologue: V(t0, jt0) 8 frags; Q(t0)
  short8 u0 = *(const short8*)(vb + (size_t)t0 * 16384 + 0);
  short8 u1 = *(const short8*)(vb + (size_t)t0 * 16384 + 512);
  short8 u2 = *(const short8*)(vb + (size_t)t0 * 16384 + 1024);
  short8 u3 = *(const short8*)(vb + (size_t)t0 * 16384 + 1536);
  short8 u4 = *(const short8*)(vb + (size_t)t0 * 16384 + 4096);
  short8 u5 = *(const short8*)(vb + (size_t)t0 * 16384 + 4096 + 512);
  short8 u6 = *(const short8*)(vb + (size_t)t0 * 16384 + 4096 + 1024);
  short8 u7 = *(const short8*)(vb + (size_t)t0 * 16384 + 4096 + 1536);
  short8 q00 = *(const short8*)(qb + (size_t)t0 * 64 * CQK);
  short8 q01 = *(const short8*)(qb + (size_t)t0 * 64 * CQK + 16);
  short8 q10 = *(const short8*)(qb + (size_t)t0 * 64 * CQK + 32 * CQK);
  short8 q11 = *(const short8*)(qb + (size_t)t0 * 64 * CQK + 32 * CQK + 16);

// exp + pack + 8 PV MFMAs for one 32-j unit across 128 ch, with the NEXT
// unit's V-frag reloads interleaved after each frag's last use.
// a0 (e0..e7) pairs with kh0 frags (u0,u1,u4,u5); a1 with kh1 (u2,u3,u6,u7).
#define EPPV(SV, NB)                                                           \
  do {                                                                         \
    float e0 = fexp2((SV)[0]), e1 = fexp2((SV)[1]);                            \
    float e2 = fexp2((SV)[2]), e3 = fexp2((SV)[3]);                            \
    float e4 = fexp2((SV)[4]), e5 = fexp2((SV)[5]);                            \
    float e6 = fexp2((SV)[6]), e7 = fexp2((SV)[7]);                            \
    float e8 = fexp2((SV)[8]), e9 = fexp2((SV)[9]);                            \
    float e10 = fexp2((SV)[10]), e11 = fexp2((SV)[11]);                        \
    float e12 = fexp2((SV)[12]), e13 = fexp2((SV)[13]);                        \
    float e14 = fexp2((SV)[14]), e15 = fexp2((SV)[15]);                        \
    ls += ((((e0 + e1) + (e2 + e3)) + ((e4 + e5) + (e6 + e7))) +               \
           (((e8 + e9) + (e10 + e11)) + ((e12 + e13) + (e14 + e15))));         \
    u32x4 pA = {pack2(e0, e1), pack2(e2, e3), pack2(e4, e5), pack2(e6, e7)};   \
    u32x4 pB = {pack2(e8, e9), pack2(e10, e11), pack2(e12, e13),               \
                pack2(e14, e15)};                                              \
    const short8 a0 = __builtin_bit_cast(short8, pA);                          \
    const short8 a1 = __builtin_bit_cast(short8, pB);                          \
    o00 = MFMA32(a0, u0, o00);                                                 \
    o01 = MFMA32(a0, u1, o01);                                                 \
    o10 = MFMA32(a0, u4, o10);                                                 \
    o11 = MFMA32(a0, u5, o11);                                                 \
    u0 = *(const short8*)((NB) + 0);                                           \
    u1 = *(const short8*)((NB) + 512);                                         \
    u4 = *(const short8*)((NB) + 4096);                                        \
    u5 = *(const short8*)((NB) + 4096 + 512);                                  \
    o00 = MFMA32(a1, u2, o00);                                                 \
    o01 = MFMA32(a1, u3, o01);                                                 \
    o10 = MFMA32(a1, u6, o10);                                                 \
    o11 = MFMA32(a1, u7, o11);                                                 \
    u2 = *(const short8*)((NB) + 1024);                                        \
    u3 = *(const short8*)((NB) + 1536);                                        \
    u6 = *(const short8*)((NB) + 4096 + 1024);                                 \
    u7 = *(const short8*)((NB) + 4096 + 1536);                                 \
  } while (0)

  for (int t = t0; t < t0 + 32; ++t) {
    const u16* tb = vb + (size_t)t * 16384;
    // S jt0 (j = t*64 .. +31): lane holds S[j rows][i=L31]
    f32x16 sv0 = MFMA32(q00, kf0, z16);
    sv0 = MFMA32(q01, kf1, sv0);
    EPPV(sv0, tb + 2048);                 // reloads -> this tile's jt1 frags
    // S jt1; Q regs dead after -> reload Q(t+1) under the MFMA latency.
    // (jsel=1, t=63 -> Q reads land at q_ws end == k_ws start: valid, unused;
    //  V reads land at vt_ws end == wtf start: valid, unused.)
    f32x16 sv1 = MFMA32(q10, kf0, z16);
    sv1 = MFMA32(q11, kf1, sv1);
    {
      const size_t qo = (size_t)(t + 1) * 64 * CQK;
      q00 = *(const short8*)(qb + qo);
      q01 = *(const short8*)(qb + qo + 16);
      q10 = *(const short8*)(qb + qo + 32 * CQK);
      q11 = *(const short8*)(qb + qo + 32 * CQK + 16);
    }
    EPPV(sv1, tb + 16384);                // reloads -> next tile's jt0 frags
  }
#undef EPPV

  // rowsum partial for i = L31 over this wave's j-half (merge Lhi halves)
  ls += __shfl_xor(ls, 32);

  // cross-wave merge: j-half partner pairs (w, w+2) share (i, ch) exactly.
  if (w >= 2) {
#pragma unroll
    for (int e = 0; e < 16; e++) {
      obuf[w - 2][L][e] = o00[e];
      obuf[w - 2][L][16 + e] = o01[e];
      obuf[w - 2][L][32 + e] = o10[e];
      obuf[w - 2][L][48 + e] = o11[e];
    }
    if (L < 32) rbuf[w - 2][L] = ls;
  }
  __syncthreads();
  if (w < 2) {
#pragma unroll
    for (int e = 0; e < 16; e++) {
      o00[e] += obuf[w][L][e];
      o01[e] += obuf[w][L][16 + e];
      o10[e] += obuf[w][L][32 + e];
      o11[e] += obuf[w][L][48 + e];
    }
    const float lst = ls + rbuf[w][L31];
    if (L < 32) lp2[w][L] = 1.0f / lst;
    asm volatile("s_waitcnt lgkmcnt(0)" ::: "memory");  // intra-wave LDS RAW

    float linv[16];
#pragma unroll
    for (int rg = 0; rg < 16; rg++)
      linv[rg] = lp2[w][(rg & 3) + 8 * (rg >> 2) + 4 * Lhi];

    const float g = gamma[0];
#define STO(OV, CB2, CT2)                                                      \
  _Pragma("unroll")                                                            \
  for (int rg = 0; rg < 16; rg++) {                                            \
    const int i = i0 + (rg & 3) + 8 * (rg >> 2) + 4 * Lhi;                     \
    const int c = (w * 2 + (CB2)) * 64 + (CT2) * 32 + L31;                     \
    const size_t idx = ((size_t)(b * NTOK + i)) * CDIM + c;                    \
    out[idx] = g * (OV[rg] * linv[rg]) + x[idx];                               \
  }
    STO(o00, 0, 0)
    STO(o01, 0, 1)
    STO(o10, 1, 0)
    STO(o11, 1, 1)
#undef STO
  }
}

// ---------------------------------------------------------------------------
extern "C" void kernel_launch(void* const* d_in, const int* in_sizes, int n_in,
                              void* d_out, int out_size, void* d_ws, size_t ws_size,
                              hipStream_t stream) {
  const float* x  = (const float*)d_in[0];
  const float* Wq = (const float*)d_in[1];
  const float* bq = (const float*)d_in[2];
  const float* Wk = (const float*)d_in[3];
  const float* bk = (const float*)d_in[4];
  const float* Wv = (const float*)d_in[5];
  const float* bv = (const float*)d_in[6];
  const float* gamma = (const float*)d_in[7];
  float* out = (float*)d_out;

  char* ws = (char*)d_ws;
  u16* q_ws  = (u16*)(ws);
  u16* k_ws  = (u16*)(ws + (2u << 20));
  u16* vt_ws = (u16*)(ws + (4u << 20));
  u16* wtf   = (u16*)(ws + (20u << 20));
  float* bias = (float*)(ws + (20u << 20) + (256u << 10));

  k_prep<<<160, 64, 0, stream>>>(Wq, bq, Wk, bk, Wv, bv, wtf, bias);
  k_proj<<<512, 256, 0, stream>>>(x, wtf, bias, q_ws, k_ws, vt_ws);
  k_attn<<<1024, 256, 0, stream>>>(x, q_ws, k_ws, vt_ws, gamma, out);
}

// Round 11
// 218.971 us; speedup vs baseline: 1.1696x; 1.1696x over previous
//
#include <hip/hip_runtime.h>

typedef __attribute__((ext_vector_type(8))) short short8;
typedef __attribute__((ext_vector_type(4))) float f32x4;
typedef __attribute__((ext_vector_type(16))) float f32x16;
typedef __attribute__((ext_vector_type(2))) unsigned int u32x2;
typedef __attribute__((ext_vector_type(4))) unsigned int u32x4;
typedef unsigned short u16;
typedef unsigned int u32;

#define MFMA16(a, b, c) __builtin_amdgcn_mfma_f32_16x16x32_bf16((a), (b), (c), 0, 0, 0)
#define MFMA32(a, b, c) __builtin_amdgcn_mfma_f32_32x32x16_bf16((a), (b), (c), 0, 0, 0)

#define BATCH 8
#define NTOK 4096
#define CDIM 256
#define CQK 32
#define LOG2E 1.4426950408889634f

__device__ __forceinline__ u16 f2bf(float f) {
  u32 u = __float_as_uint(f);
  return (u16)((u + 0x7FFFu + ((u >> 16) & 1u)) >> 16);
}
// pack two f32 -> two bf16 (round-half-up) in one u32: bf(a) | bf(b)<<16
__device__ __forceinline__ u32 pack2(float a, float b) {
  const u32 ua = __float_as_uint(a) + 0x8000u;
  const u32 ub = __float_as_uint(b) + 0x8000u;
#if __has_builtin(__builtin_amdgcn_perm)
  return __builtin_amdgcn_perm(ub, ua, 0x07060302u);  // {ua.b2,ua.b3,ub.b2,ub.b3}
#else
  return (ua >> 16) | (ub & 0xFFFF0000u);
#endif
}
__device__ __forceinline__ float fexp2(float x) {
#if __has_builtin(__builtin_amdgcn_exp2f)
  return __builtin_amdgcn_exp2f(x);
#else
  return exp2f(x);
#endif
}

// ---------------------------------------------------------------------------
// Kernel 0: weights -> MFMA B-fragment order + f32 bias.
// ---------------------------------------------------------------------------
__global__ void k_prep(const float* __restrict__ Wq, const float* __restrict__ bq,
                       const float* __restrict__ Wk, const float* __restrict__ bk,
                       const float* __restrict__ Wv, const float* __restrict__ bv,
                       u16* __restrict__ wtf, float* __restrict__ bias) {
  const int f = blockIdx.x;        // 0..159 = ct*8+ks
  const int L = threadIdx.x;       // 0..63
  const int ct = f >> 3, ks = f & 7;
  const int o = ct * 16 + (L & 15);
  const int ch = ks * 32 + (L >> 4) * 8;
  short8 v8;
#pragma unroll
  for (int jj = 0; jj < 8; jj++) {
    const int c = ch + jj;
    float v;
    if (o < 32)       v = Wq[c * CQK + o];
    else if (o < 64)  v = Wk[c * CQK + (o - 32)];
    else              v = Wv[c * CDIM + (o - 64)];
    v8[jj] = (short)f2bf(v);
  }
  *(short8*)(wtf + (size_t)f * 512 + L * 8) = v8;
  if (f == 0) {
    for (int i = L; i < 320; i += 64) {
      if (i < 32)      bias[i] = bq[i];
      else if (i < 64) bias[i] = bk[i - 32];
      else             bias[i] = bv[i - 64];
    }
  }
}

// ---------------------------------------------------------------------------
// Kernel 1: fused cvt+proj. K outputs pre-scaled by log2(e) (exp2 trick).
// q_ws/k_ws row-major [row][32]. V is emitted as ready MFMA32 B-fragments
// with the in-register-P j-permutation baked in:
//   frag(b, t=64-token tile, cg=64-ch group, fid=(jt<<2)|(kh<<1)|ct2):
//   lane l, elem jj holds V[t*64 + 32*jt + 16*kh + 4*(l>>5) + (jj&3)+8*(jj>>2)]
//                          [cg*64 + ct2*32 + (l&31)]
// so k_attn's PV consumes V global->reg with zero LDS staging and the A/B
// k-orders agree by construction (j(k) = (k&3)+8*((k>>2)&1)+4*(k>>3)).
// ---------------------------------------------------------------------------
__global__ __launch_bounds__(256, 2) void k_proj(
    const float* __restrict__ x, const u16* __restrict__ wtf,
    const float* __restrict__ bias,
    u16* __restrict__ q_ws, u16* __restrict__ k_ws, u16* __restrict__ vt_ws) {
  __shared__ u16 x_lds[64 * 264];
  __shared__ u16 vt_t[64 * 76];   // straight [c][n], pad 76 (2-way banks)
  const int m0 = blockIdx.x * 64;
  const int tid = threadIdx.x;
  const int w = tid >> 6, L = tid & 63;
  const int lr = L & 15, q4 = L >> 4;

  // ks=0 weight prefetch (independent of LDS) — flies across the x staging.
  short8 wfA[5], wfB[5];
#pragma unroll
  for (int j = 0; j < 5; j++)
    wfA[j] = *(const short8*)(wtf + ((size_t)((j * 4 + w) * 8 + 0)) * 512 + L * 8);

  // stage + convert x tile via perm-packs
#pragma unroll
  for (int ii = 0; ii < 8; ii++) {
    const int e = (tid + 256 * ii) * 8;
    const int row = e >> 8, col = e & 255;
    const float* src = x + (size_t)(m0 + row) * CDIM + col;
    f32x4 a = *(const f32x4*)src;
    f32x4 b4 = *(const f32x4*)(src + 4);
    u32x4 pk;
    pk[0] = pack2(a[0], a[1]);
    pk[1] = pack2(a[2], a[3]);
    pk[2] = pack2(b4[0], b4[1]);
    pk[3] = pack2(b4[2], b4[3]);
    *(u32x4*)&x_lds[row * 264 + col] = pk;
  }
  __syncthreads();

  f32x4 acc[4][5];
#pragma unroll
  for (int rg = 0; rg < 4; rg++)
#pragma unroll
    for (int j = 0; j < 5; j++) acc[rg][j] = (f32x4){0.f, 0.f, 0.f, 0.f};

#pragma unroll
  for (int ks = 0; ks < 8; ks++) {
    // prefetch next ks-slice into the other buffer (no barriers in this loop)
    if (ks < 7) {
#pragma unroll
      for (int j = 0; j < 5; j++) {
        short8 v = *(const short8*)(wtf +
            ((size_t)((j * 4 + w) * 8 + ks + 1)) * 512 + L * 8);
        if (ks & 1) wfA[j] = v; else wfB[j] = v;
      }
    }
#pragma unroll
    for (int rg = 0; rg < 4; rg++) {
      short8 a = *(const short8*)&x_lds[(rg * 16 + lr) * 264 + ks * 32 + q4 * 8];
#pragma unroll
      for (int j = 0; j < 5; j++)
        acc[rg][j] = MFMA16(a, (ks & 1) ? wfB[j] : wfA[j], acc[rg][j]);
    }
  }

  // q/k epilogue (j=0 -> ct = w; k scaled by log2e). Branch is wave-uniform.
  {
    const float bb = bias[w * 16 + lr];
#pragma unroll
    for (int rg = 0; rg < 4; rg++)
#pragma unroll
      for (int r = 0; r < 4; r++) {
        const int row = m0 + rg * 16 + q4 * 4 + r;
        float v = acc[rg][0][r] + bb;
        if (w < 2) q_ws[(size_t)row * CQK + w * 16 + lr] = f2bf(v);
        else       k_ws[(size_t)row * CQK + (w - 2) * 16 + lr] = f2bf(v * LOG2E);
      }
  }
  // v epilogue: straight transpose via LDS, then B-frag-linear store with
  // the PV j-permutation baked into the gather.
  const int b = m0 >> 12, nt = (m0 & 4095) >> 6;
  const int c_l = w * 16 + lr;
#pragma unroll
  for (int cg = 0; cg < 4; cg++) {
    __syncthreads();
    const int j = cg + 1;
    const float bb = bias[(4 + cg * 4 + w) * 16 + lr];
#pragma unroll
    for (int rg = 0; rg < 4; rg++) {
      u32x2 pk;
      pk[0] = pack2(acc[rg][j][0] + bb, acc[rg][j][1] + bb);
      pk[1] = pack2(acc[rg][j][2] + bb, acc[rg][j][3] + bb);
      *(u32x2*)&vt_t[c_l * 76 + rg * 16 + q4 * 4] = pk;   // straight n
    }
    __syncthreads();
    // fid is wave-uniform per store; lane gathers its 8 permuted tokens.
#pragma unroll
    for (int i = 0; i < 2; i++) {
      const int gch = tid + 256 * i;
      const int fid = gch >> 6;           // (jt<<2)|(kh<<1)|ct2
      const int lane = gch & 63;
      const int jt = fid >> 2, kh = (fid >> 1) & 1, ct2 = fid & 1;
      const int cc = ct2 * 32 + (lane & 31);
      const int n0 = jt * 32 + kh * 16 + (lane >> 5) * 4;
      u32x2 va = *(const u32x2*)&vt_t[cc * 76 + n0];       // tokens n0..n0+3
      u32x2 vb2 = *(const u32x2*)&vt_t[cc * 76 + n0 + 8];  // tokens n0+8..+11
      u32x4 vv = {va[0], va[1], vb2[0], vb2[1]};
      *(short8*)(vt_ws +
          ((((size_t)(b * 64 + nt) * 4 + cg) * 8 + fid) * 512) + lane * 8) =
          __builtin_bit_cast(short8, vv);
    }
  }
}

// ---------------------------------------------------------------------------
// Kernel 2: flash attention, in-register P, j-split — identical to r10
// EXCEPT __launch_bounds__(256,3): r10's (256,4) imposed a 128-VGPR cap on
// a ~152-reg live set -> per-iteration scratch spills (WRITE_SIZE 33->43 MB,
// MfmaUtil 22%). A 168-VGPR budget fits the live set spill-free while still
// lifting residency to 3 blocks/CU = 12 waves/CU (1.5x r9's grid-limited 8).
// Block = (b, 32 i-rows), grid 1024; wave w: ch-half = w&1, j-half = w>>1.
// Hot loop: no barriers, no LDS, fully independent waves; live V-frags = 8
// (reloads interleaved mid-EPPV after each frag's last MFMA use). End:
// O/rowsum partial merge across j-half wave pairs via padded LDS.
// ---------------------------------------------------------------------------
__global__ __launch_bounds__(256, 3) void k_attn(
    const float* __restrict__ x, const u16* __restrict__ q_ws,
    const u16* __restrict__ k_ws, const u16* __restrict__ vt_ws,
    const float* __restrict__ gamma, float* __restrict__ out) {
  __shared__ float obuf[2][64][65];     // j-half O partials (stride-65: no conflicts)
  __shared__ float rbuf[2][32];         // j-half rowsum partials
  __shared__ float lp2[2][32];          // 1/rowsum redistribution

  const int bid = blockIdx.x;
  const int b = bid & 7;                // same-b blocks land on one XCD
  const int i0 = (bid >> 3) * 32;       // 32-i window per block
  const int tid = threadIdx.x;
  const int w = tid >> 6, L = tid & 63;
  const int L31 = L & 31, Lhi = L >> 5;
  const int chh = w & 1;                // 128-ch half
  const int jsel = w >> 1;              // j-half: t in [jsel*32, jsel*32+32)
  const int t0 = jsel * 32;

  // K^T B-frags (persistent): lane holds K[i0+L31][Lhi*8 ..+8 (+16)]
  const u16* kb = k_ws + ((size_t)(b * NTOK + i0 + L31)) * CQK + Lhi * 8;
  const short8 kf0 = *(const short8*)(kb);
  const short8 kf1 = *(const short8*)(kb + 16);
  // Q A-frags: lane holds Q[j0+L31][Lhi*8 ..+8 (+16)]
  const u16* qb = q_ws + ((size_t)(b * NTOK) + L31) * CQK + Lhi * 8;
  // V frag base for this wave's 128-ch half (cg = chh*2 + cb2):
  //   + t*16384 + cb2*4096 + fid*512, fid = (jt<<2)|(kh<<1)|ct2
  const u16* vb = vt_ws + ((size_t)b << 20) + (size_t)(chh * 2) * 4096 +
                  (size_t)L * 8;

  f32x16 z16;
#pragma unroll
  for (int e = 0; e < 16; e++) z16[e] = 0.f;
  f32x16 o00 = z16, o01 = z16, o10 = z16, o11 = z16;  // [cb2][ct2]
  float ls = 0.f;

  // prologue: V(t0, jt0) 8 frags; Q(t0)
  short8 u0 = *(const short8*)(vb + (size_t)t0 * 16384 + 0);
  short8 u1 = *(const short8*)(vb + (size_t)t0 * 16384 + 512);
  short8 u2 = *(const short8*)(vb + (size_t)t0 * 16384 + 1024);
  short8 u3 = *(const short8*)(vb + (size_t)t0 * 16384 + 1536);
  short8 u4 = *(const short8*)(vb + (size_t)t0 * 16384 + 4096);
  short8 u5 = *(const short8*)(vb + (size_t)t0 * 16384 + 4096 + 512);
  short8 u6 = *(const short8*)(vb + (size_t)t0 * 16384 + 4096 + 1024);
  short8 u7 = *(const short8*)(vb + (size_t)t0 * 16384 + 4096 + 1536);
  short8 q00 = *(const short8*)(qb + (size_t)t0 * 64 * CQK);
  short8 q01 = *(const short8*)(qb + (size_t)t0 * 64 * CQK + 16);
  short8 q10 = *(const short8*)(qb + (size_t)t0 * 64 * CQK + 32 * CQK);
  short8 q11 = *(const short8*)(qb + (size_t)t0 * 64 * CQK + 32 * CQK + 16);

// exp + pack + 8 PV MFMAs for one 32-j unit across 128 ch, with the NEXT
// unit's V-frag reloads interleaved after each frag's last use.
// a0 (e0..e7) pairs with kh0 frags (u0,u1,u4,u5); a1 with kh1 (u2,u3,u6,u7).
#define EPPV(SV, NB)                                                           \
  do {                                                                         \
    float e0 = fexp2((SV)[0]), e1 = fexp2((SV)[1]);                            \
    float e2 = fexp2((SV)[2]), e3 = fexp2((SV)[3]);                            \
    float e4 = fexp2((SV)[4]), e5 = fexp2((SV)[5]);                            \
    float e6 = fexp2((SV)[6]), e7 = fexp2((SV)[7]);                            \
    float e8 = fexp2((SV)[8]), e9 = fexp2((SV)[9]);                            \
    float e10 = fexp2((SV)[10]), e11 = fexp2((SV)[11]);                        \
    float e12 = fexp2((SV)[12]), e13 = fexp2((SV)[13]);                        \
    float e14 = fexp2((SV)[14]), e15 = fexp2((SV)[15]);                        \
    ls += ((((e0 + e1) + (e2 + e3)) + ((e4 + e5) + (e6 + e7))) +               \
           (((e8 + e9) + (e10 + e11)) + ((e12 + e13) + (e14 + e15))));         \
    u32x4 pA = {pack2(e0, e1), pack2(e2, e3), pack2(e4, e5), pack2(e6, e7)};   \
    u32x4 pB = {pack2(e8, e9), pack2(e10, e11), pack2(e12, e13),               \
                pack2(e14, e15)};                                              \
    const short8 a0 = __builtin_bit_cast(short8, pA);                          \
    const short8 a1 = __builtin_bit_cast(short8, pB);                          \
    o00 = MFMA32(a0, u0, o00);                                                 \
    o01 = MFMA32(a0, u1, o01);                                                 \
    o10 = MFMA32(a0, u4, o10);                                                 \
    o11 = MFMA32(a0, u5, o11);                                                 \
    u0 = *(const short8*)((NB) + 0);                                           \
    u1 = *(const short8*)((NB) + 512);                                         \
    u4 = *(const short8*)((NB) + 4096);                                        \
    u5 = *(const short8*)((NB) + 4096 + 512);                                  \
    o00 = MFMA32(a1, u2, o00);                                                 \
    o01 = MFMA32(a1, u3, o01);                                                 \
    o10 = MFMA32(a1, u6, o10);                                                 \
    o11 = MFMA32(a1, u7, o11);                                                 \
    u2 = *(const short8*)((NB) + 1024);                                        \
    u3 = *(const short8*)((NB) + 1536);                                        \
    u6 = *(const short8*)((NB) + 4096 + 1024);                                 \
    u7 = *(const short8*)((NB) + 4096 + 1536);                                 \
  } while (0)

  for (int t = t0; t < t0 + 32; ++t) {
    const u16* tb = vb + (size_t)t * 16384;
    // S jt0 (j = t*64 .. +31): lane holds S[j rows][i=L31]
    f32x16 sv0 = MFMA32(q00, kf0, z16);
    sv0 = MFMA32(q01, kf1, sv0);
    EPPV(sv0, tb + 2048);                 // reloads -> this tile's jt1 frags
    // S jt1; Q regs dead after -> reload Q(t+1) under the MFMA latency.
    // (jsel=1, t=63 -> Q reads land at q_ws end == k_ws start: valid, unused;
    //  V reads land at vt_ws end == wtf start: valid, unused.)
    f32x16 sv1 = MFMA32(q10, kf0, z16);
    sv1 = MFMA32(q11, kf1, sv1);
    {
      const size_t qo = (size_t)(t + 1) * 64 * CQK;
      q00 = *(const short8*)(qb + qo);
      q01 = *(const short8*)(qb + qo + 16);
      q10 = *(const short8*)(qb + qo + 32 * CQK);
      q11 = *(const short8*)(qb + qo + 32 * CQK + 16);
    }
    EPPV(sv1, tb + 16384);                // reloads -> next tile's jt0 frags
  }
#undef EPPV

  // rowsum partial for i = L31 over this wave's j-half (merge Lhi halves)
  ls += __shfl_xor(ls, 32);

  // cross-wave merge: j-half partner pairs (w, w+2) share (i, ch) exactly.
  if (w >= 2) {
#pragma unroll
    for (int e = 0; e < 16; e++) {
      obuf[w - 2][L][e] = o00[e];
      obuf[w - 2][L][16 + e] = o01[e];
      obuf[w - 2][L][32 + e] = o10[e];
      obuf[w - 2][L][48 + e] = o11[e];
    }
    if (L < 32) rbuf[w - 2][L] = ls;
  }
  __syncthreads();
  if (w < 2) {
#pragma unroll
    for (int e = 0; e < 16; e++) {
      o00[e] += obuf[w][L][e];
      o01[e] += obuf[w][L][16 + e];
      o10[e] += obuf[w][L][32 + e];
      o11[e] += obuf[w][L][48 + e];
    }
    const float lst = ls + rbuf[w][L31];
    if (L < 32) lp2[w][L] = 1.0f / lst;
    asm volatile("s_waitcnt lgkmcnt(0)" ::: "memory");  // intra-wave LDS RAW

    float linv[16];
#pragma unroll
    for (int rg = 0; rg < 16; rg++)
      linv[rg] = lp2[w][(rg & 3) + 8 * (rg >> 2) + 4 * Lhi];

    const float g = gamma[0];
#define STO(OV, CB2, CT2)                                                      \
  _Pragma("unroll")                                                            \
  for (int rg = 0; rg < 16; rg++) {                                            \
    const int i = i0 + (rg & 3) + 8 * (rg >> 2) + 4 * Lhi;                     \
    const int c = (w * 2 + (CB2)) * 64 + (CT2) * 32 + L31;                     \
    const size_t idx = ((size_t)(b * NTOK + i)) * CDIM + c;                    \
    out[idx] = g * (OV[rg] * linv[rg]) + x[idx];                               \
  }
    STO(o00, 0, 0)
    STO(o01, 0, 1)
    STO(o10, 1, 0)
    STO(o11, 1, 1)
#undef STO
  }
}

// ---------------------------------------------------------------------------
extern "C" void kernel_launch(void* const* d_in, const int* in_sizes, int n_in,
                              void* d_out, int out_size, void* d_ws, size_t ws_size,
                              hipStream_t stream) {
  const float* x  = (const float*)d_in[0];
  const float* Wq = (const float*)d_in[1];
  const float* bq = (const float*)d_in[2];
  const float* Wk = (const float*)d_in[3];
  const float* bk = (const float*)d_in[4];
  const float* Wv = (const float*)d_in[5];
  const float* bv = (const float*)d_in[6];
  const float* gamma = (const float*)d_in[7];
  float* out = (float*)d_out;

  char* ws = (char*)d_ws;
  u16* q_ws  = (u16*)(ws);
  u16* k_ws  = (u16*)(ws + (2u << 20));
  u16* vt_ws = (u16*)(ws + (4u << 20));
  u16* wtf   = (u16*)(ws + (20u << 20));
  float* bias = (float*)(ws + (20u << 20) + (256u << 10));

  k_prep<<<160, 64, 0, stream>>>(Wq, bq, Wk, bk, Wv, bv, wtf, bias);
  k_proj<<<512, 256, 0, stream>>>(x, wtf, bias, q_ws, k_ws, vt_ws);
  k_attn<<<1024, 256, 0, stream>>>(x, q_ws, k_ws, vt_ws, gamma, out);
}

// Round 12
// 185.375 us; speedup vs baseline: 1.3816x; 1.1812x over previous
//
#include <hip/hip_runtime.h>

typedef __attribute__((ext_vector_type(8))) short short8;
typedef __attribute__((ext_vector_type(4))) float f32x4;
typedef __attribute__((ext_vector_type(16))) float f32x16;
typedef __attribute__((ext_vector_type(2))) unsigned int u32x2;
typedef __attribute__((ext_vector_type(4))) unsigned int u32x4;
typedef unsigned short u16;
typedef unsigned int u32;

#define MFMA16(a, b, c) __builtin_amdgcn_mfma_f32_16x16x32_bf16((a), (b), (c), 0, 0, 0)
#define MFMA32(a, b, c) __builtin_amdgcn_mfma_f32_32x32x16_bf16((a), (b), (c), 0, 0, 0)

#define BAR_VMEM() asm volatile("s_waitcnt vmcnt(0) lgkmcnt(0)\ns_barrier" ::: "memory")
#define BAR_LDS()  asm volatile("s_waitcnt lgkmcnt(0)\ns_barrier" ::: "memory")

#define BATCH 8
#define NTOK 4096
#define CDIM 256
#define CQK 32
#define LOG2E 1.4426950408889634f

__device__ __forceinline__ u16 f2bf(float f) {
  u32 u = __float_as_uint(f);
  return (u16)((u + 0x7FFFu + ((u >> 16) & 1u)) >> 16);
}
// pack two f32 -> two bf16 (round-half-up) in one u32: bf(a) | bf(b)<<16
__device__ __forceinline__ u32 pack2(float a, float b) {
  const u32 ua = __float_as_uint(a) + 0x8000u;
  const u32 ub = __float_as_uint(b) + 0x8000u;
#if __has_builtin(__builtin_amdgcn_perm)
  return __builtin_amdgcn_perm(ub, ua, 0x07060302u);  // {ua.b2,ua.b3,ub.b2,ub.b3}
#else
  return (ua >> 16) | (ub & 0xFFFF0000u);
#endif
}
__device__ __forceinline__ float fexp2(float x) {
#if __has_builtin(__builtin_amdgcn_exp2f)
  return __builtin_amdgcn_exp2f(x);
#else
  return exp2f(x);
#endif
}

// ---------------------------------------------------------------------------
// Kernel 0: weights -> MFMA B-fragment order + f32 bias.
// ---------------------------------------------------------------------------
__global__ void k_prep(const float* __restrict__ Wq, const float* __restrict__ bq,
                       const float* __restrict__ Wk, const float* __restrict__ bk,
                       const float* __restrict__ Wv, const float* __restrict__ bv,
                       u16* __restrict__ wtf, float* __restrict__ bias) {
  const int f = blockIdx.x;        // 0..159 = ct*8+ks
  const int L = threadIdx.x;       // 0..63
  const int ct = f >> 3, ks = f & 7;
  const int o = ct * 16 + (L & 15);
  const int ch = ks * 32 + (L >> 4) * 8;
  short8 v8;
#pragma unroll
  for (int jj = 0; jj < 8; jj++) {
    const int c = ch + jj;
    float v;
    if (o < 32)       v = Wq[c * CQK + o];
    else if (o < 64)  v = Wk[c * CQK + (o - 32)];
    else              v = Wv[c * CDIM + (o - 64)];
    v8[jj] = (short)f2bf(v);
  }
  *(short8*)(wtf + (size_t)f * 512 + L * 8) = v8;
  if (f == 0) {
    for (int i = L; i < 320; i += 64) {
      if (i < 32)      bias[i] = bq[i];
      else if (i < 64) bias[i] = bk[i - 32];
      else             bias[i] = bv[i - 64];
    }
  }
}

// ---------------------------------------------------------------------------
// Kernel 1: fused cvt+proj (byte-identical to the verified r5 version).
// K outputs pre-scaled by log2(e). V emitted in FRAGMENT-LINEAR layout with
// half-swap on channel bit3 baked in (matches k_attn's P half swizzle):
// frag(b,t,cg,fi=ks2*2+ct2) at (((b*64+t)*4+cg)*8+fi)*512 + lane*8.
// ---------------------------------------------------------------------------
__global__ __launch_bounds__(256, 2) void k_proj(
    const float* __restrict__ x, const u16* __restrict__ wtf,
    const float* __restrict__ bias,
    u16* __restrict__ q_ws, u16* __restrict__ k_ws, u16* __restrict__ vt_ws) {
  __shared__ u16 x_lds[64 * 264];
  __shared__ u16 vt_t[64 * 72];
  const int m0 = blockIdx.x * 64;
  const int tid = threadIdx.x;
  const int w = tid >> 6, L = tid & 63;
  const int lr = L & 15, q4 = L >> 4;

  // ks=0 weight prefetch (independent of LDS) — flies across the x staging.
  short8 wfA[5], wfB[5];
#pragma unroll
  for (int j = 0; j < 5; j++)
    wfA[j] = *(const short8*)(wtf + ((size_t)((j * 4 + w) * 8 + 0)) * 512 + L * 8);

  // stage + convert x tile via perm-packs
#pragma unroll
  for (int ii = 0; ii < 8; ii++) {
    const int e = (tid + 256 * ii) * 8;
    const int row = e >> 8, col = e & 255;
    const float* src = x + (size_t)(m0 + row) * CDIM + col;
    f32x4 a = *(const f32x4*)src;
    f32x4 b4 = *(const f32x4*)(src + 4);
    u32x4 pk;
    pk[0] = pack2(a[0], a[1]);
    pk[1] = pack2(a[2], a[3]);
    pk[2] = pack2(b4[0], b4[1]);
    pk[3] = pack2(b4[2], b4[3]);
    *(u32x4*)&x_lds[row * 264 + col] = pk;
  }
  __syncthreads();

  f32x4 acc[4][5];
#pragma unroll
  for (int rg = 0; rg < 4; rg++)
#pragma unroll
    for (int j = 0; j < 5; j++) acc[rg][j] = (f32x4){0.f, 0.f, 0.f, 0.f};

#pragma unroll
  for (int ks = 0; ks < 8; ks++) {
    // prefetch next ks-slice into the other buffer (no barriers in this loop)
    if (ks < 7) {
#pragma unroll
      for (int j = 0; j < 5; j++) {
        short8 v = *(const short8*)(wtf +
            ((size_t)((j * 4 + w) * 8 + ks + 1)) * 512 + L * 8);
        if (ks & 1) wfA[j] = v; else wfB[j] = v;
      }
    }
#pragma unroll
    for (int rg = 0; rg < 4; rg++) {
      short8 a = *(const short8*)&x_lds[(rg * 16 + lr) * 264 + ks * 32 + q4 * 8];
#pragma unroll
      for (int j = 0; j < 5; j++)
        acc[rg][j] = MFMA16(a, (ks & 1) ? wfB[j] : wfA[j], acc[rg][j]);
    }
  }

  // q/k epilogue (j=0 -> ct = w; k scaled by log2e). Branch is wave-uniform.
  {
    const float bb = bias[w * 16 + lr];
#pragma unroll
    for (int rg = 0; rg < 4; rg++)
#pragma unroll
      for (int r = 0; r < 4; r++) {
        const int row = m0 + rg * 16 + q4 * 4 + r;
        float v = acc[rg][0][r] + bb;
        if (w < 2) q_ws[(size_t)row * CQK + w * 16 + lr] = f2bf(v);
        else       k_ws[(size_t)row * CQK + (w - 2) * 16 + lr] = f2bf(v * LOG2E);
      }
  }
  // v epilogue: transpose via LDS with half-swap, then fragment-linear store.
  const int b = m0 >> 12, nt = (m0 & 4095) >> 6;
  const int rb2 = ((lr >> 3) & 1) << 2;       // row-bit3 of c_l = w*16+lr
  const int c_l = w * 16 + lr;
#pragma unroll
  for (int cg = 0; cg < 4; cg++) {
    __syncthreads();
    const int j = cg + 1;
    const float bb = bias[(4 + cg * 4 + w) * 16 + lr];
#pragma unroll
    for (int rg = 0; rg < 4; rg++) {
      const int n_base = (rg * 16 + q4 * 4) ^ rb2;  // half-swapped physical pos
      u32x2 pk;
      pk[0] = pack2(acc[rg][j][0] + bb, acc[rg][j][1] + bb);
      pk[1] = pack2(acc[rg][j][2] + bb, acc[rg][j][3] + bb);
      *(u32x2*)&vt_t[c_l * 72 + n_base] = pk;
    }
    __syncthreads();
    // fragment-linear store: consumer group == cg; frag fi = ks2*2+ct2;
    // lane holds channel ct2*32+(lane&31), j-window (ks2*2+(lane>>5))*8..+8.
#pragma unroll
    for (int i = 0; i < 2; i++) {
      const int gch = tid + 256 * i;
      const int fi = gch >> 6;            // 0..7
      const int lane = gch & 63;
      const int ks2 = fi >> 1, ct2 = fi & 1;
      short8 v = *(const short8*)&vt_t[(ct2 * 32 + (lane & 31)) * 72 +
                                       (ks2 * 2 + (lane >> 5)) * 8];
      *(short8*)(vt_ws +
          ((((size_t)(b * 64 + nt) * 4 + cg) * 8 + fi) * 512) + lane * 8) = v;
    }
  }
}

// ---------------------------------------------------------------------------
// Kernel 2: flash attention, shared-P, 128-ROW BLOCKS for V L2-reuse.
// Diagnosis: r5/r6's 90us wall was invariant to occupancy because each XCD's
// resident blocks pull 2 MB of V per iteration through that XCD's L2 (b=bid&7
// pins a batch to one XCD) — per-XCD L2 BW is the binder. Doubling rows per
// block (128 i x 64 j tiles, 8 waves, grid 256 = 1 block/CU, still 2
// waves/SIMD) halves per-XCD V traffic to 1 MB/iter at identical MFMA-busy
// per SIMD. S: wave w owns rows w*16..+16 (4 MFMA16 + 16 exps, as r5).
// PV: wave w owns ch-slice (cg=w>>1, ct2=w&1); a_p spans 4 i-groups so each
// V frag feeds 4 MFMA32. Q duplication across waves is L1-absorbed (same
// addresses). All r5 swizzle algebra unchanged: P chunk-XOR keys on row&7,
// half-flip keys on bit3 of L31 on both A(row) and B(channel) sides.
// ---------------------------------------------------------------------------
__global__ __launch_bounds__(512, 2) void k_attn(
    const float* __restrict__ x, const u16* __restrict__ q_ws,
    const u16* __restrict__ k_ws, const u16* __restrict__ vt_ws,
    const float* __restrict__ gamma, float* __restrict__ out) {
  __shared__ u16 p_lds[2][128 * 64];    // 32 KB total

  const int bid = blockIdx.x;
  const int b = bid & 7;                // same-b blocks land on one XCD
  const int it = bid >> 3;
  const int i0 = it * 128;
  const int tid = threadIdx.x;
  const int w = tid >> 6, L = tid & 63; // 8 waves
  const int lr = L & 15, q4 = L >> 4;
  const int L31 = L & 31, Lhi = L >> 5, L7 = L & 7;

  const short8 a_k = *(const short8*)(k_ws +
      ((size_t)(b * NTOK + i0 + w * 16 + lr)) * CQK + q4 * 8);

  // V fragment base for this wave's ch-slice: cg = w>>1, ct2 = w&1.
  // frag(b,t,cg,fi=ks2*2+ct2) at (((b*64+t)*4+cg)*8+fi)*512 + lane*8.
  const u16* vg = vt_ws +
      ((size_t)b * 2048 + (w >> 1) * 8 + (w & 1)) * 512 + (size_t)L * 8;
  const u16* q_base = q_ws + (size_t)b * NTOK * CQK;

  f32x16 o_acc[4];                      // ig = 0..3 (i = i0+ig*32+crow)
#pragma unroll
  for (int ig = 0; ig < 4; ig++)
#pragma unroll
    for (int e = 0; e < 16; e++) o_acc[ig][e] = 0.f;
  float lsum = 0.f;

  // P write base offset: row i = w*16+lr; half = (q4&1)^((lr>>3)&1);
  // chunk XOR keyed on lr&7 (= row&7).
  const int pw_off = (w * 16 + lr) * 64 + (((q4 & 1) ^ ((lr >> 3) & 1)) << 2);
  const int q4h = q4 >> 1;
  u16* const pl0 = &p_lds[0][0];
  u16* const pl1 = &p_lds[1][0];

// exp(s) + packed b64 swizzled P-write for j-subtile T into PW
#define EXPW(SV, T, PW)                                                          \
  do {                                                                           \
    const float p0 = fexp2((SV)[0]);                                             \
    const float p1 = fexp2((SV)[1]);                                             \
    const float p2 = fexp2((SV)[2]);                                             \
    const float p3 = fexp2((SV)[3]);                                             \
    lsum += (p0 + p1) + (p2 + p3);                                               \
    u32x2 pk;                                                                    \
    pk[0] = pack2(p0, p1);                                                       \
    pk[1] = pack2(p2, p3);                                                       \
    *(u32x2*)((PW) + (((2 * (T) + q4h) ^ (lr & 7)) * 8)) = pk;                   \
  } while (0)

  // --- prologue: Q(0)->bqA; V(0)->vV; S^T(0)+exp+P->pl0; Q(1)->bqB
  short8 bqA[4], bqB[4];
  short8 vV[4];
#pragma unroll
  for (int t = 0; t < 4; t++)
    bqA[t] = *(const short8*)(q_base + (size_t)(t * 16 + lr) * CQK + q4 * 8);
#pragma unroll
  for (int ks2 = 0; ks2 < 4; ks2++)
    vV[ks2] = *(const short8*)(vg + (size_t)ks2 * 1024);
  {
    f32x4 s0 = MFMA16(bqA[0], a_k, ((f32x4){0.f, 0.f, 0.f, 0.f}));
    f32x4 s1 = MFMA16(bqA[1], a_k, ((f32x4){0.f, 0.f, 0.f, 0.f}));
    f32x4 s2 = MFMA16(bqA[2], a_k, ((f32x4){0.f, 0.f, 0.f, 0.f}));
    f32x4 s3 = MFMA16(bqA[3], a_k, ((f32x4){0.f, 0.f, 0.f, 0.f}));
    u16* pwn = pl0 + pw_off;
    EXPW(s0, 0, pwn);
    EXPW(s1, 1, pwn);
    EXPW(s2, 2, pwn);
    EXPW(s3, 3, pwn);
  }
#pragma unroll
  for (int t = 0; t < 4; t++)
    bqB[t] = *(const short8*)(q_base + (size_t)(64 + t * 16 + lr) * CQK + q4 * 8);

// One iteration: LDS-only barrier; S^T(JT+1) from BQN regs; Q(JT+2)->BQF;
// PV(JT) from PL_CUR + vV regs (a_p spans 4 i-groups), with exp(JT+1)->PL_NXT
// and V(JT+1) reloads interleaved per ks2.
#define ATTN_ITER(JT, PL_CUR, PL_NXT, BQN, BQF, DO_Q)                            \
  do {                                                                           \
    BAR_LDS(); /* all P(JT) writes visible; PL_NXT free for overwrite */         \
    f32x4 s0 = MFMA16(BQN[0], a_k, ((f32x4){0.f, 0.f, 0.f, 0.f}));               \
    f32x4 s1 = MFMA16(BQN[1], a_k, ((f32x4){0.f, 0.f, 0.f, 0.f}));               \
    f32x4 s2 = MFMA16(BQN[2], a_k, ((f32x4){0.f, 0.f, 0.f, 0.f}));               \
    f32x4 s3 = MFMA16(BQN[3], a_k, ((f32x4){0.f, 0.f, 0.f, 0.f}));               \
    if (DO_Q) {                                                                  \
      _Pragma("unroll")                                                          \
      for (int t = 0; t < 4; t++)                                                \
        BQF[t] = *(const short8*)(q_base +                                       \
                 (size_t)((JT) * 64 + 128 + t * 16 + lr) * CQK + q4 * 8);        \
    }                                                                            \
    u16* pwn = (PL_NXT) + pw_off;                                                \
    _Pragma("unroll")                                                            \
    for (int ks2 = 0; ks2 < 4; ks2++) {                                          \
      const int slot = (((ks2 * 2 + Lhi) ^ L7)) * 8;                             \
      short8 a_p0 = *(const short8*)((PL_CUR) + (L31) * 64 + slot);              \
      short8 a_p1 = *(const short8*)((PL_CUR) + (32 + L31) * 64 + slot);         \
      short8 a_p2 = *(const short8*)((PL_CUR) + (64 + L31) * 64 + slot);         \
      short8 a_p3 = *(const short8*)((PL_CUR) + (96 + L31) * 64 + slot);         \
      o_acc[0] = MFMA32(a_p0, vV[ks2], o_acc[0]);                                \
      o_acc[1] = MFMA32(a_p1, vV[ks2], o_acc[1]);                                \
      o_acc[2] = MFMA32(a_p2, vV[ks2], o_acc[2]);                                \
      o_acc[3] = MFMA32(a_p3, vV[ks2], o_acc[3]);                                \
      vV[ks2] = *(const short8*)(vg +                                            \
          (size_t)((JT) + 1) * 16384 + ks2 * 1024);                              \
      if (ks2 == 0) EXPW(s0, 0, pwn);                                            \
      if (ks2 == 1) EXPW(s1, 1, pwn);                                            \
      if (ks2 == 2) EXPW(s2, 2, pwn);                                            \
      if (ks2 == 3) EXPW(s3, 3, pwn);                                            \
    }                                                                            \
  } while (0)

  for (int jt2 = 0; jt2 < 62; jt2 += 2) {
    ATTN_ITER(jt2,     pl0, pl1, bqB, bqA, 1);
    ATTN_ITER(jt2 + 1, pl1, pl0, bqA, bqB, 1);
  }
  // t=62: computes S(63)+P->pl1, loads V(63); no Q(64) prefetch.
  ATTN_ITER(62, pl0, pl1, bqB, bqA, 0);
#undef ATTN_ITER

  // t=63: PV only.
  BAR_LDS();
#pragma unroll
  for (int ks2 = 0; ks2 < 4; ks2++) {
    const int slot = (((ks2 * 2 + Lhi) ^ L7)) * 8;
    short8 a_p0 = *(const short8*)(pl1 + (L31) * 64 + slot);
    short8 a_p1 = *(const short8*)(pl1 + (32 + L31) * 64 + slot);
    short8 a_p2 = *(const short8*)(pl1 + (64 + L31) * 64 + slot);
    short8 a_p3 = *(const short8*)(pl1 + (96 + L31) * 64 + slot);
    o_acc[0] = MFMA32(a_p0, vV[ks2], o_acc[0]);
    o_acc[1] = MFMA32(a_p1, vV[ks2], o_acc[1]);
    o_acc[2] = MFMA32(a_p2, vV[ks2], o_acc[2]);
    o_acc[3] = MFMA32(a_p3, vV[ks2], o_acc[3]);
  }
#undef EXPW

  // softmax denominators: rows partitioned by wave (w*16+lr); sum over q4.
  float s2 = lsum;
  s2 += __shfl_xor(s2, 16);
  s2 += __shfl_xor(s2, 32);
  const float rl = 1.0f / s2;
  BAR_LDS();
  float* lp = (float*)pl0;              // 128 floats
  if (q4 == 0) lp[w * 16 + lr] = rl;
  BAR_LDS();

  float linv[4][16];
#pragma unroll
  for (int ig = 0; ig < 4; ig++)
#pragma unroll
    for (int rg = 0; rg < 16; rg++)
      linv[ig][rg] = lp[ig * 32 + (rg & 3) + 8 * (rg >> 2) + 4 * Lhi];

  const float g = gamma[0];
  const int c = (w >> 1) * 64 + (w & 1) * 32 + L31;
#pragma unroll
  for (int ig = 0; ig < 4; ig++)
#pragma unroll
    for (int rg = 0; rg < 16; rg++) {
      const int i = i0 + ig * 32 + (rg & 3) + 8 * (rg >> 2) + 4 * Lhi;
      const size_t idx = ((size_t)(b * NTOK + i)) * CDIM + c;
      out[idx] = g * (o_acc[ig][rg] * linv[ig][rg]) + x[idx];
    }
}

// ---------------------------------------------------------------------------
extern "C" void kernel_launch(void* const* d_in, const int* in_sizes, int n_in,
                              void* d_out, int out_size, void* d_ws, size_t ws_size,
                              hipStream_t stream) {
  const float* x  = (const float*)d_in[0];
  const float* Wq = (const float*)d_in[1];
  const float* bq = (const float*)d_in[2];
  const float* Wk = (const float*)d_in[3];
  const float* bk = (const float*)d_in[4];
  const float* Wv = (const float*)d_in[5];
  const float* bv = (const float*)d_in[6];
  const float* gamma = (const float*)d_in[7];
  float* out = (float*)d_out;

  char* ws = (char*)d_ws;
  u16* q_ws  = (u16*)(ws);
  u16* k_ws  = (u16*)(ws + (2u << 20));
  u16* vt_ws = (u16*)(ws + (4u << 20));
  u16* wtf   = (u16*)(ws + (20u << 20));
  float* bias = (float*)(ws + (20u << 20) + (256u << 10));

  k_prep<<<160, 64, 0, stream>>>(Wq, bq, Wk, bk, Wv, bv, wtf, bias);
  k_proj<<<512, 256, 0, stream>>>(x, wtf, bias, q_ws, k_ws, vt_ws);
  k_attn<<<256, 512, 0, stream>>>(x, q_ws, k_ws, vt_ws, gamma, out);
}